// Round 7
// baseline (1301.914 us; speedup 1.0000x reference)
//
#include <hip/hip_runtime.h>
#include <hip/hip_bf16.h>
#include <hip/hip_fp16.h>

#define N_NODES 50000
#define F_IN    64
#define HDIM    256
#define E_EDGES 800000
#define G_GRAPHS 2048
#define L_LAYERS 4
#define T_OUT   4
#define BN_EPS  1e-5f

#define NPAD    50176   // 196 * 256
#define NBLK    196
#define LDK     264     // fp16 LDS row stride

#define NSEG    8       // feature segments (one per XCD via blockIdx%8)
#define SEGF    32      // features per segment (64B = 1 cache line per edge)
#define NB      16      // nodes per block (4 per wave)

typedef _Float16 half8 __attribute__((ext_vector_type(8)));
typedef float    f32x4 __attribute__((ext_vector_type(4)));

// ---- degree ----------------------------------------------------------------
__global__ void k_deg_count(const int* __restrict__ dst, int* __restrict__ cnt) {
    int e = blockIdx.x * blockDim.x + threadIdx.x;
    if (e < E_EDGES) atomicAdd(&cnt[dst[e]], 1);
}

// ---- two-level scan --------------------------------------------------------
__global__ void k_scan1(const int* __restrict__ cnt, int* __restrict__ iscan,
                        int* __restrict__ bsum) {
    __shared__ int sm[256];
    int t = threadIdx.x, i = blockIdx.x * 256 + t;
    sm[t] = cnt[i];
    __syncthreads();
    for (int off = 1; off < 256; off <<= 1) {
        int u = (t >= off) ? sm[t - off] : 0;
        __syncthreads();
        sm[t] += u;
        __syncthreads();
    }
    iscan[i] = sm[t];
    if (t == 255) bsum[blockIdx.x] = sm[255];
}

__global__ void k_scan2(const int* __restrict__ bsum, int* __restrict__ boff) {
    __shared__ int sm[256];
    int t = threadIdx.x;
    int v = (t < NBLK) ? bsum[t] : 0;
    sm[t] = v;
    __syncthreads();
    for (int off = 1; off < 256; off <<= 1) {
        int u = (t >= off) ? sm[t - off] : 0;
        __syncthreads();
        sm[t] += u;
        __syncthreads();
    }
    if (t < NBLK) boff[t] = sm[t] - v;   // exclusive
}

__global__ void k_scan3(const int* __restrict__ cnt, const int* __restrict__ iscan,
                        const int* __restrict__ boff, int* __restrict__ rowptr,
                        int* __restrict__ wpos, float* __restrict__ inv) {
    int i = blockIdx.x * 256 + threadIdx.x;
    int c = cnt[i];
    int excl = boff[blockIdx.x] + iscan[i] - c;
    rowptr[i] = excl;
    wpos[i] = excl;
    inv[i] = rsqrtf((float)c + 1.0f);
}

// ---- scatter edges into CSR order (src ids fit in ushort: N < 65536) -------
__global__ void k_scatter(const int* __restrict__ ei, int* __restrict__ wpos,
                          ushort* __restrict__ csr_src) {
    int e = blockIdx.x * blockDim.x + threadIdx.x;
    if (e < E_EDGES) {
        int s = ei[e];
        int d = ei[E_EDGES + e];
        int pos = atomicAdd(&wpos[d], 1);
        csr_src[pos] = (ushort)s;
    }
}

// ---- weight convert: Wt[l][n][k] = fp16(W[l][k][n]) ------------------------
__global__ void k_wcvt(const float* __restrict__ W, _Float16* __restrict__ Wt) {
    int l = blockIdx.x >> 8;       // layer
    int k = blockIdx.x & 255;      // k-row
    int n = threadIdx.x;           // col
    float v = W[(((size_t)l * 256) + k) * 256 + n];
    Wt[(((size_t)l * 256) + n) * 256 + k] = (_Float16)v;
}

// ---- proj GEMM (f32, K=64): h = relu(x @ W + b); writes f32 + fp16 sidecar -
__global__ __launch_bounds__(256) void k_gemm_proj(const float* __restrict__ A,
                                                   const float* __restrict__ W,
                                                   const float* __restrict__ bias,
                                                   float* __restrict__ outf,
                                                   ushort* __restrict__ outh, int nrows) {
    __shared__ float hs[64][F_IN];
    int block_r = blockIdx.x * 64;
    const float4* A4 = (const float4*)A;
    float4* hs4 = (float4*)&hs[0][0];
    const int tot4 = 64 * F_IN / 4;
    int base4 = block_r * (F_IN / 4);
    for (int i = threadIdx.x; i < tot4; i += 256) {
        int row = block_r + (i * 4) / F_IN;
        hs4[i] = (row < nrows) ? A4[base4 + i] : make_float4(0.f, 0.f, 0.f, 0.f);
    }
    __syncthreads();

    int c0 = (threadIdx.x & 63) * 4;
    int r0 = (threadIdx.x >> 6) * 16;
    float4 acc[16];
#pragma unroll
    for (int i = 0; i < 16; i++) acc[i] = make_float4(0.f, 0.f, 0.f, 0.f);

    for (int k = 0; k < F_IN; k += 4) {
        float4 w0 = *(const float4*)(W + (size_t)(k + 0) * HDIM + c0);
        float4 w1 = *(const float4*)(W + (size_t)(k + 1) * HDIM + c0);
        float4 w2 = *(const float4*)(W + (size_t)(k + 2) * HDIM + c0);
        float4 w3 = *(const float4*)(W + (size_t)(k + 3) * HDIM + c0);
#pragma unroll
        for (int i = 0; i < 16; i++) {
            float4 hv = *(const float4*)&hs[r0 + i][k];
            acc[i].x += hv.x * w0.x + hv.y * w1.x + hv.z * w2.x + hv.w * w3.x;
            acc[i].y += hv.x * w0.y + hv.y * w1.y + hv.z * w2.y + hv.w * w3.y;
            acc[i].z += hv.x * w0.z + hv.y * w1.z + hv.z * w2.z + hv.w * w3.z;
            acc[i].w += hv.x * w0.w + hv.y * w1.w + hv.z * w2.w + hv.w * w3.w;
        }
    }

#pragma unroll
    for (int i = 0; i < 16; i++) {
        int row = block_r + r0 + i;
        if (row >= nrows) break;
        float4 v = acc[i];
        float4 b = *(const float4*)(bias + c0);
        v.x = fmaxf(v.x + b.x, 0.f);
        v.y = fmaxf(v.y + b.y, 0.f);
        v.z = fmaxf(v.z + b.z, 0.f);
        v.w = fmaxf(v.w + b.w, 0.f);
        *(float4*)(outf + (size_t)row * HDIM + c0) = v;
        __half2 lo = __floats2half2_rn(v.x, v.y);
        __half2 hi = __floats2half2_rn(v.z, v.w);
        uint2 u;
        u.x = *(unsigned int*)&lo;
        u.y = *(unsigned int*)&hi;
        *(uint2*)(outh + (size_t)row * HDIM + c0) = u;
    }
}

// ---- conv GEMM via MFMA: hWh = fp16((h16 @ W) * inv[row]) ------------------
__global__ __launch_bounds__(256) void k_gemm_mfma(const ushort* __restrict__ h16,
                                                   const _Float16* __restrict__ Wt,
                                                   const float* __restrict__ inv,
                                                   _Float16* __restrict__ outh, int nrows) {
    __shared__ _Float16 hs[64 * LDK];
    int block_r = blockIdx.x * 64;
    for (int i = threadIdx.x; i < 64 * 32; i += 256) {
        int row = i >> 5;
        int c16 = (i & 31) * 8;
        uint4 v;
        if (block_r + row < nrows)
            v = *(const uint4*)(h16 + (size_t)(block_r + row) * HDIM + c16);
        else
            v = make_uint4(0u, 0u, 0u, 0u);
        *(uint4*)&hs[row * LDK + c16] = v;
    }
    __syncthreads();

    int wave = threadIdx.x >> 6;
    int lane = threadIdx.x & 63;
    int l16 = lane & 15;
    int quad = lane >> 4;
    int n0 = wave * 64;

    f32x4 acc[4][4] = {};
    for (int k0 = 0; k0 < HDIM; k0 += 32) {
        half8 a[4], b[4];
#pragma unroll
        for (int ai = 0; ai < 4; ai++)
            a[ai] = *(const half8*)&hs[(ai * 16 + l16) * LDK + k0 + quad * 8];
#pragma unroll
        for (int bj = 0; bj < 4; bj++)
            b[bj] = *(const half8*)&Wt[(size_t)(n0 + bj * 16 + l16) * HDIM + k0 + quad * 8];
#pragma unroll
        for (int ai = 0; ai < 4; ai++)
#pragma unroll
            for (int bj = 0; bj < 4; bj++)
                acc[ai][bj] = __builtin_amdgcn_mfma_f32_16x16x32_f16(a[ai], b[bj], acc[ai][bj], 0, 0, 0);
    }

#pragma unroll
    for (int ai = 0; ai < 4; ai++) {
        int rowb = block_r + ai * 16 + quad * 4;
#pragma unroll
        for (int r = 0; r < 4; r++) {
            int row = rowb + r;
            if (row >= nrows) continue;
            float sc = inv[row];
#pragma unroll
            for (int bj = 0; bj < 4; bj++) {
                outh[(size_t)row * HDIM + n0 + bj * 16 + l16] = (_Float16)(acc[ai][bj][r] * sc);
            }
        }
    }
}

// ---- feature-sliced CSR aggregation (XCD-local L2 working set) -------------
// blockIdx%8 = segment (32 feats, 64B/row); blockIdx/8 = node group of NB.
// Wave: 16 edge slots x 4 granules; butterfly all-reduce over edge slots.
__global__ __launch_bounds__(256) void k_aggr_seg(const int* __restrict__ rowptr,
                                                  const ushort* __restrict__ csr,
                                                  const ushort* __restrict__ hWh,
                                                  const float* __restrict__ inv,
                                                  const float* __restrict__ cb,
                                                  const float* __restrict__ gamma,
                                                  const float* __restrict__ beta,
                                                  const float* __restrict__ mean,
                                                  const float* __restrict__ var,
                                                  float* __restrict__ h,
                                                  ushort* __restrict__ h16out) {
    int seg  = blockIdx.x & (NSEG - 1);
    int grp  = blockIdx.x >> 3;
    int wave = threadIdx.x >> 6;
    int lane = threadIdx.x & 63;
    int f = lane & 3;          // granule within segment (8 fp16 feats)
    int e = lane >> 2;         // edge slot 0..15
    int gran0 = seg * 4;       // granule base within row (row = 32 granules)
    const uint4* tbl = (const uint4*)hWh;

    for (int nn = 0; nn < 4; nn++) {
        int node = grp * NB + wave * 4 + nn;
        if (node >= N_NODES) break;

        float acc[8];
#pragma unroll
        for (int i = 0; i < 8; i++) acc[i] = 0.f;

        int beg = rowptr[node], end = rowptr[node + 1];
        for (int base = beg; base < end; base += 64) {
            int m = end - base; if (m > 64) m = 64;
            int myidx = (lane < m) ? (int)csr[base + lane] : 0;
            for (int j = 0; j < m; j += 16) {
                int slot = j + e;
                int s = __shfl(myidx, (slot < m) ? slot : 0);
                if (slot < m) {
                    uint4 u = tbl[(size_t)s * 32 + gran0 + f];
                    const __half2* p = (const __half2*)&u;
#pragma unroll
                    for (int i = 0; i < 4; i++) {
                        float2 t = __half22float2(p[i]);
                        acc[2 * i]     += t.x;
                        acc[2 * i + 1] += t.y;
                    }
                }
            }
        }

        // butterfly all-reduce over edge-slot bits (lane bits 2..5)
#pragma unroll
        for (int i = 0; i < 8; i++) {
            acc[i] += __shfl_xor(acc[i], 4);
            acc[i] += __shfl_xor(acc[i], 8);
            acc[i] += __shfl_xor(acc[i], 16);
            acc[i] += __shfl_xor(acc[i], 32);
        }

        if (e == 0) {   // lanes 0..3 own granule f
            // self-loop term
            uint4 us = tbl[(size_t)node * 32 + gran0 + f];
            const __half2* ps = (const __half2*)&us;
#pragma unroll
            for (int i = 0; i < 4; i++) {
                float2 t = __half22float2(ps[i]);
                acc[2 * i]     += t.x;
                acc[2 * i + 1] += t.y;
            }
            int c0 = seg * SEGF + f * 8;
            float iv = inv[node];
            float r8[8];
#pragma unroll
            for (int half = 0; half < 2; half++) {
                int c = c0 + half * 4;
                float4 bb = *(const float4*)(cb + c);
                float4 gm = *(const float4*)(gamma + c);
                float4 bt = *(const float4*)(beta + c);
                float4 mn = *(const float4*)(mean + c);
                float4 vr = *(const float4*)(var + c);
                float4 ho = *(const float4*)(h + (size_t)node * HDIM + c);
                float* a = &acc[half * 4];
                float4 r;
                r.x = fmaxf((a[0] * iv + bb.x - mn.x) * rsqrtf(vr.x + BN_EPS) * gm.x + bt.x, 0.f) + ho.x;
                r.y = fmaxf((a[1] * iv + bb.y - mn.y) * rsqrtf(vr.y + BN_EPS) * gm.y + bt.y, 0.f) + ho.y;
                r.z = fmaxf((a[2] * iv + bb.z - mn.z) * rsqrtf(vr.z + BN_EPS) * gm.z + bt.z, 0.f) + ho.z;
                r.w = fmaxf((a[3] * iv + bb.w - mn.w) * rsqrtf(vr.w + BN_EPS) * gm.w + bt.w, 0.f) + ho.w;
                *(float4*)(h + (size_t)node * HDIM + c) = r;
                r8[half * 4 + 0] = r.x; r8[half * 4 + 1] = r.y;
                r8[half * 4 + 2] = r.z; r8[half * 4 + 3] = r.w;
            }
            __half2 q0 = __floats2half2_rn(r8[0], r8[1]);
            __half2 q1 = __floats2half2_rn(r8[2], r8[3]);
            __half2 q2 = __floats2half2_rn(r8[4], r8[5]);
            __half2 q3 = __floats2half2_rn(r8[6], r8[7]);
            uint4 uo;
            uo.x = *(unsigned int*)&q0; uo.y = *(unsigned int*)&q1;
            uo.z = *(unsigned int*)&q2; uo.w = *(unsigned int*)&q3;
            *(uint4*)(h16out + (size_t)node * HDIM + c0) = uo;
        }
    }
}

// ---- pooling: per-graph mean and max over sorted batch ---------------------
__global__ void k_pool(const float* __restrict__ h, const int* __restrict__ batch,
                       float* __restrict__ gp) {
    int g = blockIdx.x;
    __shared__ int s_lo, s_hi;
    if (threadIdx.x == 0) {
        int lo = 0, hi = N_NODES;
        while (lo < hi) { int m = (lo + hi) >> 1; if (batch[m] < g) lo = m + 1; else hi = m; }
        s_lo = lo;
        hi = N_NODES;
        while (lo < hi) { int m = (lo + hi) >> 1; if (batch[m] < g + 1) lo = m + 1; else hi = m; }
        s_hi = lo;
    }
    __syncthreads();
    int lo = s_lo, hi = s_hi;
    int t = threadIdx.x;
    float sum = 0.0f, mx = -1e30f;
    for (int n = lo; n < hi; n++) {
        float v = h[(size_t)n * HDIM + t];
        sum += v;
        mx = fmaxf(mx, v);
    }
    float cntf = fmaxf((float)(hi - lo), 1.0f);
    gp[(size_t)g * 2 * HDIM + t] = sum / cntf;
    gp[(size_t)g * 2 * HDIM + HDIM + t] = (hi > lo) ? mx : 0.0f;
}

// ---- head ------------------------------------------------------------------
__global__ void k_head1(const float* __restrict__ gp, const float* __restrict__ W1,
                        const float* __restrict__ b1, float* __restrict__ g1) {
    int g = blockIdx.x;
    int t = threadIdx.x;
    __shared__ float gs[2 * HDIM];
    gs[t] = gp[(size_t)g * 2 * HDIM + t];
    gs[HDIM + t] = gp[(size_t)g * 2 * HDIM + HDIM + t];
    __syncthreads();
    float acc = b1[t];
#pragma unroll 8
    for (int k = 0; k < 2 * HDIM; k++) acc += gs[k] * W1[k * HDIM + t];
    g1[(size_t)g * HDIM + t] = fmaxf(acc, 0.0f);
}

__global__ void k_head2(const float* __restrict__ g1, const float* __restrict__ W2,
                        const float* __restrict__ b2, float* __restrict__ g2) {
    int g = blockIdx.x;
    int t = threadIdx.x;  // 0..127
    __shared__ float gs[HDIM];
    gs[t] = g1[(size_t)g * HDIM + t];
    gs[128 + t] = g1[(size_t)g * HDIM + 128 + t];
    __syncthreads();
    float acc = b2[t];
#pragma unroll 8
    for (int k = 0; k < HDIM; k++) acc += gs[k] * W2[k * 128 + t];
    g2[(size_t)g * 128 + t] = fmaxf(acc, 0.0f);
}

__global__ void k_head3(const float* __restrict__ g2, const float* __restrict__ W3,
                        const float* __restrict__ b3, float* __restrict__ out) {
    int g = blockIdx.x;
    int t = threadIdx.x;  // 0..63
    __shared__ float gs[128];
    gs[t] = g2[(size_t)g * 128 + t];
    gs[64 + t] = g2[(size_t)g * 128 + 64 + t];
    __syncthreads();
    if (t < T_OUT) {
        float acc = b3[t];
#pragma unroll 8
        for (int k = 0; k < 128; k++) acc += gs[k] * W3[k * T_OUT + t];
        out[(size_t)g * T_OUT + t] = acc;
    }
}

extern "C" void kernel_launch(void* const* d_in, const int* in_sizes, int n_in,
                              void* d_out, int out_size, void* d_ws, size_t ws_size,
                              hipStream_t stream) {
    const float* x     = (const float*)d_in[0];
    const int*   ei    = (const int*)d_in[1];
    const int*   batch = (const int*)d_in[2];
    const float* projW = (const float*)d_in[3];
    const float* projb = (const float*)d_in[4];
    const float* convW = (const float*)d_in[5];
    const float* convb = (const float*)d_in[6];
    const float* gamma = (const float*)d_in[7];
    const float* beta  = (const float*)d_in[8];
    const float* mean  = (const float*)d_in[9];
    const float* var   = (const float*)d_in[10];
    const float* W1    = (const float*)d_in[11];
    const float* b1    = (const float*)d_in[12];
    const float* W2    = (const float*)d_in[13];
    const float* b2    = (const float*)d_in[14];
    const float* W3    = (const float*)d_in[15];
    const float* b3    = (const float*)d_in[16];
    float* out = (float*)d_out;

    // workspace layout (all segments 16B aligned)
    float*  wsf    = (float*)d_ws;
    float*  inv    = wsf;                        // NPAD f
    int*    cnt    = (int*)(wsf + NPAD);         // NPAD i
    int*    rowptr = cnt + NPAD;                 // NPAD i
    int*    wpos   = rowptr + NPAD;              // NPAD i
    int*    iscan  = wpos + NPAD;                // NPAD i
    int*    bsum   = iscan + NPAD;               // 256 i
    int*    boff   = bsum + 256;                 // 256 i
    ushort* csr    = (ushort*)(boff + 256);      // 800256 u16
    float*  h      = (float*)(csr + 800256);     // N*H f
    ushort* hWh    = (ushort*)(h + (size_t)N_NODES * HDIM);   // N*H fp16
    ushort* h16    = hWh + (size_t)N_NODES * HDIM;            // N*H fp16 sidecar
    float*  gp     = (float*)(h16 + (size_t)N_NODES * HDIM);  // G*2H
    float*  g1     = gp + (size_t)G_GRAPHS * 2 * HDIM;        // G*H
    float*  g2     = g1 + (size_t)G_GRAPHS * HDIM;            // G*128
    _Float16* Wt   = (_Float16*)(g2 + (size_t)G_GRAPHS * 128); // L*H*H fp16

    // ---- CSR build + weight convert ----
    hipMemsetAsync(cnt, 0, NPAD * sizeof(int), stream);
    k_deg_count<<<(E_EDGES + 255) / 256, 256, 0, stream>>>(ei + E_EDGES, cnt);
    k_scan1<<<NBLK, 256, 0, stream>>>(cnt, iscan, bsum);
    k_scan2<<<1, 256, 0, stream>>>(bsum, boff);
    k_scan3<<<NBLK, 256, 0, stream>>>(cnt, iscan, boff, rowptr, wpos, inv);
    k_scatter<<<(E_EDGES + 255) / 256, 256, 0, stream>>>(ei, wpos, csr);
    k_wcvt<<<L_LAYERS * 256, 256, 0, stream>>>(convW, Wt);

    // ---- proj ----
    int gemm_blocks = (N_NODES + 63) / 64;
    k_gemm_proj<<<gemm_blocks, 256, 0, stream>>>(x, projW, projb, h, h16, N_NODES);

    // ---- GCN layers ----
    int aggr_blocks = ((N_NODES + NB - 1) / NB) * NSEG;
    for (int l = 0; l < L_LAYERS; l++) {
        k_gemm_mfma<<<gemm_blocks, 256, 0, stream>>>(h16, Wt + (size_t)l * HDIM * HDIM,
                                                     inv, (_Float16*)hWh, N_NODES);
        k_aggr_seg<<<aggr_blocks, 256, 0, stream>>>(rowptr, csr, hWh, inv,
                                                    convb + l * HDIM, gamma + l * HDIM,
                                                    beta + l * HDIM, mean + l * HDIM,
                                                    var + l * HDIM, h, h16);
    }

    // ---- pool + head ----
    k_pool<<<G_GRAPHS, HDIM, 0, stream>>>(h, batch, gp);
    k_head1<<<G_GRAPHS, HDIM, 0, stream>>>(gp, W1, b1, g1);
    k_head2<<<G_GRAPHS, 128, 0, stream>>>(g1, W2, b2, g2);
    k_head3<<<G_GRAPHS, 64, 0, stream>>>(g2, W3, b3, out);
}

// Round 8
// 650.865 us; speedup vs baseline: 2.0003x; 2.0003x over previous
//
#include <hip/hip_runtime.h>
#include <hip/hip_bf16.h>
#include <hip/hip_fp16.h>

#define N_NODES 50000
#define F_IN    64
#define HDIM    256
#define E_EDGES 800000
#define G_GRAPHS 2048
#define L_LAYERS 4
#define T_OUT   4
#define BN_EPS  1e-5f

#define NPAD    50176   // 196 * 256
#define NBLK    196
#define LDK     264     // fp16 LDS row stride for K=256 tiles

// Wt buffer offsets (fp16 elements)
#define WT_CONV 0
#define WT_PROJ 262144
#define WT_H1   278528
#define WT_H2   409600
#define WT_TOT  442368

typedef _Float16 half8 __attribute__((ext_vector_type(8)));
typedef float    f32x4 __attribute__((ext_vector_type(4)));

// ---- degree ----------------------------------------------------------------
__global__ void k_deg_count(const int* __restrict__ dst, int* __restrict__ cnt) {
    int e = blockIdx.x * blockDim.x + threadIdx.x;
    if (e < E_EDGES) atomicAdd(&cnt[dst[e]], 1);
}

// ---- two-level scan --------------------------------------------------------
__global__ void k_scan1(const int* __restrict__ cnt, int* __restrict__ iscan,
                        int* __restrict__ bsum) {
    __shared__ int sm[256];
    int t = threadIdx.x, i = blockIdx.x * 256 + t;
    sm[t] = cnt[i];
    __syncthreads();
    for (int off = 1; off < 256; off <<= 1) {
        int u = (t >= off) ? sm[t - off] : 0;
        __syncthreads();
        sm[t] += u;
        __syncthreads();
    }
    iscan[i] = sm[t];
    if (t == 255) bsum[blockIdx.x] = sm[255];
}

__global__ void k_scan2(const int* __restrict__ bsum, int* __restrict__ boff) {
    __shared__ int sm[256];
    int t = threadIdx.x;
    int v = (t < NBLK) ? bsum[t] : 0;
    sm[t] = v;
    __syncthreads();
    for (int off = 1; off < 256; off <<= 1) {
        int u = (t >= off) ? sm[t - off] : 0;
        __syncthreads();
        sm[t] += u;
        __syncthreads();
    }
    if (t < NBLK) boff[t] = sm[t] - v;   // exclusive
}

__global__ void k_scan3(const int* __restrict__ cnt, const int* __restrict__ iscan,
                        const int* __restrict__ boff, int* __restrict__ rowptr,
                        int* __restrict__ wpos, float* __restrict__ inv) {
    int i = blockIdx.x * 256 + threadIdx.x;
    int c = cnt[i];
    int excl = boff[blockIdx.x] + iscan[i] - c;
    rowptr[i] = excl;
    wpos[i] = excl;
    inv[i] = rsqrtf((float)c + 1.0f);
}

// ---- scatter edges into CSR order (src ids fit in ushort: N < 65536) -------
__global__ void k_scatter(const int* __restrict__ ei, int* __restrict__ wpos,
                          ushort* __restrict__ csr_src) {
    int e = blockIdx.x * blockDim.x + threadIdx.x;
    if (e < E_EDGES) {
        int s = ei[e];
        int d = ei[E_EDGES + e];
        int pos = atomicAdd(&wpos[d], 1);
        csr_src[pos] = (ushort)s;
    }
}

// ---- all weight transposes -> fp16 [n][k], one dispatch --------------------
__global__ void k_wcvt_all(const float* __restrict__ convW, const float* __restrict__ projW,
                           const float* __restrict__ W1, const float* __restrict__ W2,
                           _Float16* __restrict__ Wt) {
    int i = blockIdx.x * 256 + threadIdx.x;
    if (i < 262144) {                       // conv: 4 x [256x256]
        int l = i >> 16, r = i & 65535;
        int k = r >> 8, n = r & 255;
        Wt[WT_CONV + (size_t)l * 65536 + n * 256 + k] = (_Float16)convW[(size_t)l * 65536 + k * 256 + n];
        return;
    }
    i -= 262144;
    if (i < 16384) {                        // proj: [64x256] -> [256][64]
        int k = i >> 8, n = i & 255;
        Wt[WT_PROJ + n * 64 + k] = (_Float16)projW[k * 256 + n];
        return;
    }
    i -= 16384;
    if (i < 131072) {                       // W1: [512x256] -> [256][512]
        int k = i >> 8, n = i & 255;
        Wt[WT_H1 + n * 512 + k] = (_Float16)W1[k * 256 + n];
        return;
    }
    i -= 131072;
    {                                       // W2: [256x128] -> [128][256]
        int k = i >> 7, n = i & 127;
        Wt[WT_H2 + n * 256 + k] = (_Float16)W2[k * 128 + n];
    }
}

// ---- proj GEMM via MFMA: h = relu(x @ Wp + b), h f32 + fp16 sidecar --------
__global__ __launch_bounds__(256) void k_proj_mfma(const float* __restrict__ x,
                                                   const _Float16* __restrict__ Wpt,
                                                   const float* __restrict__ bias,
                                                   float* __restrict__ h,
                                                   ushort* __restrict__ h16, int nrows) {
    __shared__ _Float16 hs[64 * 72];
    int block_r = blockIdx.x * 64;
    for (int i = threadIdx.x; i < 64 * 16; i += 256) {
        int row = i >> 4;
        int c4 = (i & 15) * 4;
        float4 v = (block_r + row < nrows)
                       ? *(const float4*)(x + (size_t)(block_r + row) * F_IN + c4)
                       : make_float4(0.f, 0.f, 0.f, 0.f);
        _Float16* p = &hs[row * 72 + c4];
        p[0] = (_Float16)v.x; p[1] = (_Float16)v.y;
        p[2] = (_Float16)v.z; p[3] = (_Float16)v.w;
    }
    __syncthreads();

    int wave = threadIdx.x >> 6;
    int lane = threadIdx.x & 63;
    int l16 = lane & 15;
    int quad = lane >> 4;
    int n0 = wave * 64;

    f32x4 acc[4][4] = {};
#pragma unroll
    for (int k0 = 0; k0 < F_IN; k0 += 32) {
        half8 a[4], b[4];
#pragma unroll
        for (int ai = 0; ai < 4; ai++)
            a[ai] = *(const half8*)&hs[(ai * 16 + l16) * 72 + k0 + quad * 8];
#pragma unroll
        for (int bj = 0; bj < 4; bj++)
            b[bj] = *(const half8*)&Wpt[(size_t)(n0 + bj * 16 + l16) * F_IN + k0 + quad * 8];
#pragma unroll
        for (int ai = 0; ai < 4; ai++)
#pragma unroll
            for (int bj = 0; bj < 4; bj++)
                acc[ai][bj] = __builtin_amdgcn_mfma_f32_16x16x32_f16(a[ai], b[bj], acc[ai][bj], 0, 0, 0);
    }

#pragma unroll
    for (int ai = 0; ai < 4; ai++) {
        int rowb = block_r + ai * 16 + quad * 4;
#pragma unroll
        for (int r = 0; r < 4; r++) {
            int row = rowb + r;
            if (row >= nrows) continue;
#pragma unroll
            for (int bj = 0; bj < 4; bj++) {
                int col = n0 + bj * 16 + l16;
                float v = fmaxf(acc[ai][bj][r] + bias[col], 0.f);
                h[(size_t)row * HDIM + col] = v;
                h16[(size_t)row * HDIM + col] = __half_as_ushort(__float2half(v));
            }
        }
    }
}

// ---- conv GEMM via MFMA: hWh = fp16((h16 @ W) * inv[row]) ------------------
__global__ __launch_bounds__(256) void k_gemm_mfma(const ushort* __restrict__ h16,
                                                   const _Float16* __restrict__ Wt,
                                                   const float* __restrict__ inv,
                                                   _Float16* __restrict__ outh, int nrows) {
    __shared__ _Float16 hs[64 * LDK];
    int block_r = blockIdx.x * 64;
    for (int i = threadIdx.x; i < 64 * 32; i += 256) {
        int row = i >> 5;
        int c16 = (i & 31) * 8;
        uint4 v;
        if (block_r + row < nrows)
            v = *(const uint4*)(h16 + (size_t)(block_r + row) * HDIM + c16);
        else
            v = make_uint4(0u, 0u, 0u, 0u);
        *(uint4*)&hs[row * LDK + c16] = v;
    }
    __syncthreads();

    int wave = threadIdx.x >> 6;
    int lane = threadIdx.x & 63;
    int l16 = lane & 15;
    int quad = lane >> 4;
    int n0 = wave * 64;

    f32x4 acc[4][4] = {};
    for (int k0 = 0; k0 < HDIM; k0 += 32) {
        half8 a[4], b[4];
#pragma unroll
        for (int ai = 0; ai < 4; ai++)
            a[ai] = *(const half8*)&hs[(ai * 16 + l16) * LDK + k0 + quad * 8];
#pragma unroll
        for (int bj = 0; bj < 4; bj++)
            b[bj] = *(const half8*)&Wt[(size_t)(n0 + bj * 16 + l16) * HDIM + k0 + quad * 8];
#pragma unroll
        for (int ai = 0; ai < 4; ai++)
#pragma unroll
            for (int bj = 0; bj < 4; bj++)
                acc[ai][bj] = __builtin_amdgcn_mfma_f32_16x16x32_f16(a[ai], b[bj], acc[ai][bj], 0, 0, 0);
    }

#pragma unroll
    for (int ai = 0; ai < 4; ai++) {
        int rowb = block_r + ai * 16 + quad * 4;
#pragma unroll
        for (int r = 0; r < 4; r++) {
            int row = rowb + r;
            if (row >= nrows) continue;
            float sc = inv[row];
#pragma unroll
            for (int bj = 0; bj < 4; bj++) {
                outh[(size_t)row * HDIM + n0 + bj * 16 + l16] = (_Float16)(acc[ai][bj][r] * sc);
            }
        }
    }
}

// ---- fused CSR aggregation + self-loop + bias + BN + relu + residual -------
// wave per node. Row = 512B = 32 lanes x 16B; g=lane>>5 picks edge slot.
__global__ __launch_bounds__(256) void k_aggr(const int* __restrict__ rowptr,
                                              const ushort* __restrict__ csr,
                                              const ushort* __restrict__ hWh,
                                              const float* __restrict__ inv,
                                              const float* __restrict__ cb,
                                              const float* __restrict__ gamma,
                                              const float* __restrict__ beta,
                                              const float* __restrict__ mean,
                                              const float* __restrict__ var,
                                              float* __restrict__ h,
                                              ushort* __restrict__ h16out) {
    int node = blockIdx.x * 4 + (threadIdx.x >> 6);
    if (node >= N_NODES) return;
    int lane = threadIdx.x & 63;
    int g = lane >> 5;     // edge sub-slot (0/1)
    int f = lane & 31;     // 16B granule: features f*8 .. f*8+7
    const uint4* tbl = (const uint4*)hWh;   // row = 32 granules

    float acc[8];
#pragma unroll
    for (int i = 0; i < 8; i++) acc[i] = 0.f;

    int beg = rowptr[node], end = rowptr[node + 1];
    for (int base = beg; base < end; base += 64) {
        int m = end - base; if (m > 64) m = 64;
        int myidx = (lane < m) ? (int)csr[base + lane] : 0;
        int jj = 0;
        for (; jj + 8 <= m; jj += 8) {
            int s0 = __shfl(myidx, jj + 0 + g);
            int s1 = __shfl(myidx, jj + 2 + g);
            int s2 = __shfl(myidx, jj + 4 + g);
            int s3 = __shfl(myidx, jj + 6 + g);
            uint4 u0 = tbl[(size_t)s0 * 32 + f];
            uint4 u1 = tbl[(size_t)s1 * 32 + f];
            uint4 u2 = tbl[(size_t)s2 * 32 + f];
            uint4 u3 = tbl[(size_t)s3 * 32 + f];
            const __half2* p0 = (const __half2*)&u0;
            const __half2* p1 = (const __half2*)&u1;
            const __half2* p2 = (const __half2*)&u2;
            const __half2* p3 = (const __half2*)&u3;
#pragma unroll
            for (int i = 0; i < 4; i++) {
                float2 t0 = __half22float2(p0[i]);
                float2 t1 = __half22float2(p1[i]);
                float2 t2 = __half22float2(p2[i]);
                float2 t3 = __half22float2(p3[i]);
                acc[2 * i]     += (t0.x + t1.x) + (t2.x + t3.x);
                acc[2 * i + 1] += (t0.y + t1.y) + (t2.y + t3.y);
            }
        }
        for (; jj < m; jj += 2) {
            int e = jj + g;
            int s = __shfl(myidx, (e < m) ? e : (m - 1));
            uint4 u = tbl[(size_t)s * 32 + f];
            if (e < m) {
                const __half2* p = (const __half2*)&u;
#pragma unroll
                for (int i = 0; i < 4; i++) {
                    float2 t = __half22float2(p[i]);
                    acc[2 * i] += t.x;
                    acc[2 * i + 1] += t.y;
                }
            }
        }
    }

#pragma unroll
    for (int i = 0; i < 8; i++) acc[i] += __shfl_xor(acc[i], 32);

    if (g == 0) {
        uint4 us = tbl[(size_t)node * 32 + f];
        const __half2* ps = (const __half2*)&us;
#pragma unroll
        for (int i = 0; i < 4; i++) {
            float2 t = __half22float2(ps[i]);
            acc[2 * i] += t.x;
            acc[2 * i + 1] += t.y;
        }
        int c0 = f * 8;
        float iv = inv[node];
        float r8[8];
#pragma unroll
        for (int half = 0; half < 2; half++) {
            int c = c0 + half * 4;
            float4 bb = *(const float4*)(cb + c);
            float4 gm = *(const float4*)(gamma + c);
            float4 bt = *(const float4*)(beta + c);
            float4 mn = *(const float4*)(mean + c);
            float4 vr = *(const float4*)(var + c);
            float4 ho = *(const float4*)(h + (size_t)node * HDIM + c);
            float* a = &acc[half * 4];
            float4 r;
            r.x = fmaxf((a[0] * iv + bb.x - mn.x) * rsqrtf(vr.x + BN_EPS) * gm.x + bt.x, 0.f) + ho.x;
            r.y = fmaxf((a[1] * iv + bb.y - mn.y) * rsqrtf(vr.y + BN_EPS) * gm.y + bt.y, 0.f) + ho.y;
            r.z = fmaxf((a[2] * iv + bb.z - mn.z) * rsqrtf(vr.z + BN_EPS) * gm.z + bt.z, 0.f) + ho.z;
            r.w = fmaxf((a[3] * iv + bb.w - mn.w) * rsqrtf(vr.w + BN_EPS) * gm.w + bt.w, 0.f) + ho.w;
            *(float4*)(h + (size_t)node * HDIM + c) = r;
            r8[half * 4 + 0] = r.x; r8[half * 4 + 1] = r.y;
            r8[half * 4 + 2] = r.z; r8[half * 4 + 3] = r.w;
        }
        if (h16out) {
            __half2 q0 = __floats2half2_rn(r8[0], r8[1]);
            __half2 q1 = __floats2half2_rn(r8[2], r8[3]);
            __half2 q2 = __floats2half2_rn(r8[4], r8[5]);
            __half2 q3 = __floats2half2_rn(r8[6], r8[7]);
            uint4 uo;
            uo.x = *(unsigned int*)&q0; uo.y = *(unsigned int*)&q1;
            uo.z = *(unsigned int*)&q2; uo.w = *(unsigned int*)&q3;
            *(uint4*)(h16out + (size_t)node * HDIM + c0) = uo;
        }
    }
}

// ---- pooling: per-graph mean and max, writes fp16 gp -----------------------
__global__ void k_pool(const float* __restrict__ h, const int* __restrict__ batch,
                       ushort* __restrict__ gp16) {
    int g = blockIdx.x;
    __shared__ int s_lo, s_hi;
    if (threadIdx.x == 0) {
        int lo = 0, hi = N_NODES;
        while (lo < hi) { int m = (lo + hi) >> 1; if (batch[m] < g) lo = m + 1; else hi = m; }
        s_lo = lo;
        hi = N_NODES;
        while (lo < hi) { int m = (lo + hi) >> 1; if (batch[m] < g + 1) lo = m + 1; else hi = m; }
        s_hi = lo;
    }
    __syncthreads();
    int lo = s_lo, hi = s_hi;
    int t = threadIdx.x;
    float sum = 0.0f, mx = -1e30f;
    for (int n = lo; n < hi; n++) {
        float v = h[(size_t)n * HDIM + t];
        sum += v;
        mx = fmaxf(mx, v);
    }
    float cntf = fmaxf((float)(hi - lo), 1.0f);
    float mean = sum / cntf;
    float mxo = (hi > lo) ? mx : 0.0f;
    gp16[(size_t)g * 2 * HDIM + t] = __half_as_ushort(__float2half(mean));
    gp16[(size_t)g * 2 * HDIM + HDIM + t] = __half_as_ushort(__float2half(mxo));
}

// ---- head GEMMs via MFMA ---------------------------------------------------
// A fp16 [2048, K], B Wt fp16 [NC][K]; block = 64 rows x NC cols, NC/64 waves.
// OUT16: write relu fp16; else write relu f32.
template <int K, bool OUT16>
__global__ void k_head_mfma(const ushort* __restrict__ A, const _Float16* __restrict__ Bt,
                            const float* __restrict__ bias, ushort* __restrict__ out16,
                            float* __restrict__ outf) {
    constexpr int LDKH = K + 8;
    __shared__ _Float16 hs[64 * LDKH];
    int block_r = blockIdx.x * 64;
    for (int i = threadIdx.x; i < 64 * (K / 8); i += blockDim.x) {
        int row = i / (K / 8);
        int c = (i % (K / 8)) * 8;
        *(uint4*)&hs[row * LDKH + c] = *(const uint4*)(A + (size_t)(block_r + row) * K + c);
    }
    __syncthreads();

    int wave = threadIdx.x >> 6;
    int lane = threadIdx.x & 63;
    int l16 = lane & 15;
    int quad = lane >> 4;
    int n0 = wave * 64;

    f32x4 acc[4][4] = {};
    for (int k0 = 0; k0 < K; k0 += 32) {
        half8 a[4], b[4];
#pragma unroll
        for (int ai = 0; ai < 4; ai++)
            a[ai] = *(const half8*)&hs[(ai * 16 + l16) * LDKH + k0 + quad * 8];
#pragma unroll
        for (int bj = 0; bj < 4; bj++)
            b[bj] = *(const half8*)&Bt[(size_t)(n0 + bj * 16 + l16) * K + k0 + quad * 8];
#pragma unroll
        for (int ai = 0; ai < 4; ai++)
#pragma unroll
            for (int bj = 0; bj < 4; bj++)
                acc[ai][bj] = __builtin_amdgcn_mfma_f32_16x16x32_f16(a[ai], b[bj], acc[ai][bj], 0, 0, 0);
    }

    int ncols = blockDim.x;   // waves*64
#pragma unroll
    for (int ai = 0; ai < 4; ai++) {
        int rowb = block_r + ai * 16 + quad * 4;
#pragma unroll
        for (int r = 0; r < 4; r++) {
            int row = rowb + r;
#pragma unroll
            for (int bj = 0; bj < 4; bj++) {
                int col = n0 + bj * 16 + l16;
                float v = fmaxf(acc[ai][bj][r] + bias[col], 0.f);
                if (OUT16)
                    out16[(size_t)row * ncols + col] = __half_as_ushort(__float2half(v));
                else
                    outf[(size_t)row * ncols + col] = v;
            }
        }
    }
}

__global__ void k_head3(const float* __restrict__ g2, const float* __restrict__ W3,
                        const float* __restrict__ b3, float* __restrict__ out) {
    int g = blockIdx.x;
    int t = threadIdx.x;  // 0..63
    __shared__ float gs[128];
    gs[t] = g2[(size_t)g * 128 + t];
    gs[64 + t] = g2[(size_t)g * 128 + 64 + t];
    __syncthreads();
    if (t < T_OUT) {
        float acc = b3[t];
#pragma unroll 8
        for (int k = 0; k < 128; k++) acc += gs[k] * W3[k * T_OUT + t];
        out[(size_t)g * T_OUT + t] = acc;
    }
}

extern "C" void kernel_launch(void* const* d_in, const int* in_sizes, int n_in,
                              void* d_out, int out_size, void* d_ws, size_t ws_size,
                              hipStream_t stream) {
    const float* x     = (const float*)d_in[0];
    const int*   ei    = (const int*)d_in[1];
    const int*   batch = (const int*)d_in[2];
    const float* projW = (const float*)d_in[3];
    const float* projb = (const float*)d_in[4];
    const float* convW = (const float*)d_in[5];
    const float* convb = (const float*)d_in[6];
    const float* gamma = (const float*)d_in[7];
    const float* beta  = (const float*)d_in[8];
    const float* mean  = (const float*)d_in[9];
    const float* var   = (const float*)d_in[10];
    const float* W1    = (const float*)d_in[11];
    const float* b1    = (const float*)d_in[12];
    const float* W2    = (const float*)d_in[13];
    const float* b2    = (const float*)d_in[14];
    const float* W3    = (const float*)d_in[15];
    const float* b3    = (const float*)d_in[16];
    float* out = (float*)d_out;

    // workspace layout (all segments 16B aligned)
    float*  wsf    = (float*)d_ws;
    float*  inv    = wsf;                        // NPAD f
    int*    cnt    = (int*)(wsf + NPAD);         // NPAD i
    int*    rowptr = cnt + NPAD;                 // NPAD i
    int*    wpos   = rowptr + NPAD;              // NPAD i
    int*    iscan  = wpos + NPAD;                // NPAD i
    int*    bsum   = iscan + NPAD;               // 256 i
    int*    boff   = bsum + 256;                 // 256 i
    ushort* csr    = (ushort*)(boff + 256);      // 800256 u16
    float*  h      = (float*)(csr + 800256);     // N*H f
    ushort* hWh    = (ushort*)(h + (size_t)N_NODES * HDIM);   // N*H fp16
    ushort* h16    = hWh + (size_t)N_NODES * HDIM;            // N*H fp16 sidecar
    ushort* gp16   = h16 + (size_t)N_NODES * HDIM;            // G*512 fp16
    ushort* g1h    = gp16 + (size_t)G_GRAPHS * 512;           // G*256 fp16
    float*  g2     = (float*)(g1h + (size_t)G_GRAPHS * 256);  // G*128 f32
    _Float16* Wt   = (_Float16*)(g2 + (size_t)G_GRAPHS * 128); // WT_TOT fp16

    // ---- CSR build + weight transposes ----
    hipMemsetAsync(cnt, 0, NPAD * sizeof(int), stream);
    k_deg_count<<<(E_EDGES + 255) / 256, 256, 0, stream>>>(ei + E_EDGES, cnt);
    k_scan1<<<NBLK, 256, 0, stream>>>(cnt, iscan, bsum);
    k_scan2<<<1, 256, 0, stream>>>(bsum, boff);
    k_scan3<<<NBLK, 256, 0, stream>>>(cnt, iscan, boff, rowptr, wpos, inv);
    k_scatter<<<(E_EDGES + 255) / 256, 256, 0, stream>>>(ei, wpos, csr);
    k_wcvt_all<<<(WT_TOT + 255) / 256, 256, 0, stream>>>(convW, projW, W1, W2, Wt);

    // ---- proj (MFMA) ----
    int gemm_blocks = (N_NODES + 63) / 64;
    k_proj_mfma<<<gemm_blocks, 256, 0, stream>>>(x, Wt + WT_PROJ, projb, h, h16, N_NODES);

    // ---- GCN layers ----
    for (int l = 0; l < L_LAYERS; l++) {
        k_gemm_mfma<<<gemm_blocks, 256, 0, stream>>>(h16, Wt + WT_CONV + (size_t)l * HDIM * HDIM,
                                                     inv, (_Float16*)hWh, N_NODES);
        ushort* sidecar = (l < L_LAYERS - 1) ? h16 : nullptr;
        k_aggr<<<(N_NODES + 3) / 4, 256, 0, stream>>>(rowptr, csr, hWh, inv,
                                                      convb + l * HDIM, gamma + l * HDIM,
                                                      beta + l * HDIM, mean + l * HDIM,
                                                      var + l * HDIM, h, sidecar);
    }

    // ---- pool + head ----
    k_pool<<<G_GRAPHS, HDIM, 0, stream>>>(h, batch, gp16);
    k_head_mfma<512, true><<<G_GRAPHS / 64, 256, 0, stream>>>(gp16, Wt + WT_H1, b1, g1h, nullptr);
    k_head_mfma<256, false><<<G_GRAPHS / 64, 128, 0, stream>>>(g1h, Wt + WT_H2, b2, nullptr, g2);
    k_head3<<<G_GRAPHS, 64, 0, stream>>>(g2, W3, b3, out);
}

// Round 9
// 607.451 us; speedup vs baseline: 2.1432x; 1.0715x over previous
//
#include <hip/hip_runtime.h>
#include <hip/hip_bf16.h>
#include <hip/hip_fp16.h>

#define N_NODES 50000
#define F_IN    64
#define HDIM    256
#define E_EDGES 800000
#define G_GRAPHS 2048
#define L_LAYERS 4
#define T_OUT   4
#define BN_EPS  1e-5f

#define NPAD    50176   // 196 * 256
#define NBLK    196
#define LDK     264     // fp16 LDS row stride for K=256 tiles

// Wt buffer offsets (fp16 elements)
#define WT_CONV 0
#define WT_PROJ 262144
#define WT_H1   278528
#define WT_H2   409600
#define WT_TOT  442368

typedef _Float16 half8 __attribute__((ext_vector_type(8)));
typedef float    f32x4 __attribute__((ext_vector_type(4)));

// ---- degree ----------------------------------------------------------------
__global__ void k_deg_count(const int* __restrict__ dst, int* __restrict__ cnt) {
    int e = blockIdx.x * blockDim.x + threadIdx.x;
    if (e < E_EDGES) atomicAdd(&cnt[dst[e]], 1);
}

// ---- two-level scan --------------------------------------------------------
__global__ void k_scan1(const int* __restrict__ cnt, int* __restrict__ iscan,
                        int* __restrict__ bsum) {
    __shared__ int sm[256];
    int t = threadIdx.x, i = blockIdx.x * 256 + t;
    sm[t] = cnt[i];
    __syncthreads();
    for (int off = 1; off < 256; off <<= 1) {
        int u = (t >= off) ? sm[t - off] : 0;
        __syncthreads();
        sm[t] += u;
        __syncthreads();
    }
    iscan[i] = sm[t];
    if (t == 255) bsum[blockIdx.x] = sm[255];
}

__global__ void k_scan2(const int* __restrict__ bsum, int* __restrict__ boff) {
    __shared__ int sm[256];
    int t = threadIdx.x;
    int v = (t < NBLK) ? bsum[t] : 0;
    sm[t] = v;
    __syncthreads();
    for (int off = 1; off < 256; off <<= 1) {
        int u = (t >= off) ? sm[t - off] : 0;
        __syncthreads();
        sm[t] += u;
        __syncthreads();
    }
    if (t < NBLK) boff[t] = sm[t] - v;   // exclusive
}

__global__ void k_scan3(const int* __restrict__ cnt, const int* __restrict__ iscan,
                        const int* __restrict__ boff, int* __restrict__ rowptr,
                        int* __restrict__ wpos, float* __restrict__ inv) {
    int i = blockIdx.x * 256 + threadIdx.x;
    int c = cnt[i];
    int excl = boff[blockIdx.x] + iscan[i] - c;
    rowptr[i] = excl;
    wpos[i] = excl;
    inv[i] = rsqrtf((float)c + 1.0f);
}

// ---- scatter edges into CSR order (src ids fit in ushort: N < 65536) -------
__global__ void k_scatter(const int* __restrict__ ei, int* __restrict__ wpos,
                          ushort* __restrict__ csr_src) {
    int e = blockIdx.x * blockDim.x + threadIdx.x;
    if (e < E_EDGES) {
        int s = ei[e];
        int d = ei[E_EDGES + e];
        int pos = atomicAdd(&wpos[d], 1);
        csr_src[pos] = (ushort)s;
    }
}

// ---- all weight transposes -> fp16 [n][k], one dispatch --------------------
__global__ void k_wcvt_all(const float* __restrict__ convW, const float* __restrict__ projW,
                           const float* __restrict__ W1, const float* __restrict__ W2,
                           _Float16* __restrict__ Wt) {
    int i = blockIdx.x * 256 + threadIdx.x;
    if (i < 262144) {                       // conv: 4 x [256x256]
        int l = i >> 16, r = i & 65535;
        int k = r >> 8, n = r & 255;
        Wt[WT_CONV + (size_t)l * 65536 + n * 256 + k] = (_Float16)convW[(size_t)l * 65536 + k * 256 + n];
        return;
    }
    i -= 262144;
    if (i < 16384) {                        // proj: [64x256] -> [256][64]
        int k = i >> 8, n = i & 255;
        Wt[WT_PROJ + n * 64 + k] = (_Float16)projW[k * 256 + n];
        return;
    }
    i -= 16384;
    if (i < 131072) {                       // W1: [512x256] -> [256][512]
        int k = i >> 8, n = i & 255;
        Wt[WT_H1 + n * 512 + k] = (_Float16)W1[k * 256 + n];
        return;
    }
    i -= 131072;
    {                                       // W2: [256x128] -> [128][256]
        int k = i >> 7, n = i & 127;
        Wt[WT_H2 + n * 256 + k] = (_Float16)W2[k * 128 + n];
    }
}

// ---- proj GEMM via MFMA: h16 = fp16(relu(x @ Wp + b)) ----------------------
__global__ __launch_bounds__(256) void k_proj_mfma(const float* __restrict__ x,
                                                   const _Float16* __restrict__ Wpt,
                                                   const float* __restrict__ bias,
                                                   ushort* __restrict__ h16, int nrows) {
    __shared__ _Float16 hs[64 * 72];
    int block_r = blockIdx.x * 64;
    for (int i = threadIdx.x; i < 64 * 16; i += 256) {
        int row = i >> 4;
        int c4 = (i & 15) * 4;
        float4 v = (block_r + row < nrows)
                       ? *(const float4*)(x + (size_t)(block_r + row) * F_IN + c4)
                       : make_float4(0.f, 0.f, 0.f, 0.f);
        _Float16* p = &hs[row * 72 + c4];
        p[0] = (_Float16)v.x; p[1] = (_Float16)v.y;
        p[2] = (_Float16)v.z; p[3] = (_Float16)v.w;
    }
    __syncthreads();

    int wave = threadIdx.x >> 6;
    int lane = threadIdx.x & 63;
    int l16 = lane & 15;
    int quad = lane >> 4;
    int n0 = wave * 64;

    f32x4 acc[4][4] = {};
#pragma unroll
    for (int k0 = 0; k0 < F_IN; k0 += 32) {
        half8 a[4], b[4];
#pragma unroll
        for (int ai = 0; ai < 4; ai++)
            a[ai] = *(const half8*)&hs[(ai * 16 + l16) * 72 + k0 + quad * 8];
#pragma unroll
        for (int bj = 0; bj < 4; bj++)
            b[bj] = *(const half8*)&Wpt[(size_t)(n0 + bj * 16 + l16) * F_IN + k0 + quad * 8];
#pragma unroll
        for (int ai = 0; ai < 4; ai++)
#pragma unroll
            for (int bj = 0; bj < 4; bj++)
                acc[ai][bj] = __builtin_amdgcn_mfma_f32_16x16x32_f16(a[ai], b[bj], acc[ai][bj], 0, 0, 0);
    }

#pragma unroll
    for (int ai = 0; ai < 4; ai++) {
        int rowb = block_r + ai * 16 + quad * 4;
#pragma unroll
        for (int r = 0; r < 4; r++) {
            int row = rowb + r;
            if (row >= nrows) continue;
#pragma unroll
            for (int bj = 0; bj < 4; bj++) {
                int col = n0 + bj * 16 + l16;
                float v = fmaxf(acc[ai][bj][r] + bias[col], 0.f);
                h16[(size_t)row * HDIM + col] = __half_as_ushort(__float2half(v));
            }
        }
    }
}

// ---- conv GEMM via MFMA: hWh = fp16((h16 @ W) * inv[row]) ------------------
__global__ __launch_bounds__(256) void k_gemm_mfma(const ushort* __restrict__ h16,
                                                   const _Float16* __restrict__ Wt,
                                                   const float* __restrict__ inv,
                                                   _Float16* __restrict__ outh, int nrows) {
    __shared__ _Float16 hs[64 * LDK];
    int block_r = blockIdx.x * 64;
    for (int i = threadIdx.x; i < 64 * 32; i += 256) {
        int row = i >> 5;
        int c16 = (i & 31) * 8;
        uint4 v;
        if (block_r + row < nrows)
            v = *(const uint4*)(h16 + (size_t)(block_r + row) * HDIM + c16);
        else
            v = make_uint4(0u, 0u, 0u, 0u);
        *(uint4*)&hs[row * LDK + c16] = v;
    }
    __syncthreads();

    int wave = threadIdx.x >> 6;
    int lane = threadIdx.x & 63;
    int l16 = lane & 15;
    int quad = lane >> 4;
    int n0 = wave * 64;

    f32x4 acc[4][4] = {};
    for (int k0 = 0; k0 < HDIM; k0 += 32) {
        half8 a[4], b[4];
#pragma unroll
        for (int ai = 0; ai < 4; ai++)
            a[ai] = *(const half8*)&hs[(ai * 16 + l16) * LDK + k0 + quad * 8];
#pragma unroll
        for (int bj = 0; bj < 4; bj++)
            b[bj] = *(const half8*)&Wt[(size_t)(n0 + bj * 16 + l16) * HDIM + k0 + quad * 8];
#pragma unroll
        for (int ai = 0; ai < 4; ai++)
#pragma unroll
            for (int bj = 0; bj < 4; bj++)
                acc[ai][bj] = __builtin_amdgcn_mfma_f32_16x16x32_f16(a[ai], b[bj], acc[ai][bj], 0, 0, 0);
    }

#pragma unroll
    for (int ai = 0; ai < 4; ai++) {
        int rowb = block_r + ai * 16 + quad * 4;
#pragma unroll
        for (int r = 0; r < 4; r++) {
            int row = rowb + r;
            if (row >= nrows) continue;
            float sc = inv[row];
#pragma unroll
            for (int bj = 0; bj < 4; bj++) {
                outh[(size_t)row * HDIM + n0 + bj * 16 + l16] = (_Float16)(acc[ai][bj][r] * sc);
            }
        }
    }
}

// ---- fused CSR aggregation + self-loop + bias + BN + relu + residual -------
// Residual stream lives in fp16 (h16), updated in place.
__global__ __launch_bounds__(256) void k_aggr(const int* __restrict__ rowptr,
                                              const ushort* __restrict__ csr,
                                              const ushort* __restrict__ hWh,
                                              const float* __restrict__ inv,
                                              const float* __restrict__ cb,
                                              const float* __restrict__ gamma,
                                              const float* __restrict__ beta,
                                              const float* __restrict__ mean,
                                              const float* __restrict__ var,
                                              ushort* __restrict__ h16) {
    int node = blockIdx.x * 4 + (threadIdx.x >> 6);
    if (node >= N_NODES) return;
    int lane = threadIdx.x & 63;
    int g = lane >> 5;     // edge sub-slot (0/1)
    int f = lane & 31;     // 16B granule: features f*8 .. f*8+7
    const uint4* tbl = (const uint4*)hWh;   // row = 32 granules

    float acc[8];
#pragma unroll
    for (int i = 0; i < 8; i++) acc[i] = 0.f;

    int beg = rowptr[node], end = rowptr[node + 1];
    for (int base = beg; base < end; base += 64) {
        int m = end - base; if (m > 64) m = 64;
        int myidx = (lane < m) ? (int)csr[base + lane] : 0;
        int jj = 0;
        for (; jj + 8 <= m; jj += 8) {
            int s0 = __shfl(myidx, jj + 0 + g);
            int s1 = __shfl(myidx, jj + 2 + g);
            int s2 = __shfl(myidx, jj + 4 + g);
            int s3 = __shfl(myidx, jj + 6 + g);
            uint4 u0 = tbl[(size_t)s0 * 32 + f];
            uint4 u1 = tbl[(size_t)s1 * 32 + f];
            uint4 u2 = tbl[(size_t)s2 * 32 + f];
            uint4 u3 = tbl[(size_t)s3 * 32 + f];
            const __half2* p0 = (const __half2*)&u0;
            const __half2* p1 = (const __half2*)&u1;
            const __half2* p2 = (const __half2*)&u2;
            const __half2* p3 = (const __half2*)&u3;
#pragma unroll
            for (int i = 0; i < 4; i++) {
                float2 t0 = __half22float2(p0[i]);
                float2 t1 = __half22float2(p1[i]);
                float2 t2 = __half22float2(p2[i]);
                float2 t3 = __half22float2(p3[i]);
                acc[2 * i]     += (t0.x + t1.x) + (t2.x + t3.x);
                acc[2 * i + 1] += (t0.y + t1.y) + (t2.y + t3.y);
            }
        }
        for (; jj < m; jj += 2) {
            int e = jj + g;
            int s = __shfl(myidx, (e < m) ? e : (m - 1));
            uint4 u = tbl[(size_t)s * 32 + f];
            if (e < m) {
                const __half2* p = (const __half2*)&u;
#pragma unroll
                for (int i = 0; i < 4; i++) {
                    float2 t = __half22float2(p[i]);
                    acc[2 * i] += t.x;
                    acc[2 * i + 1] += t.y;
                }
            }
        }
    }

#pragma unroll
    for (int i = 0; i < 8; i++) acc[i] += __shfl_xor(acc[i], 32);

    if (g == 0) {
        // self-loop term
        uint4 us = tbl[(size_t)node * 32 + f];
        const __half2* ps = (const __half2*)&us;
#pragma unroll
        for (int i = 0; i < 4; i++) {
            float2 t = __half22float2(ps[i]);
            acc[2 * i] += t.x;
            acc[2 * i + 1] += t.y;
        }
        int c0 = f * 8;
        float iv = inv[node];
        // residual from fp16 stream
        uint4 ur = *(const uint4*)(h16 + (size_t)node * HDIM + c0);
        const __half2* pr = (const __half2*)&ur;
        float resv[8];
#pragma unroll
        for (int i = 0; i < 4; i++) {
            float2 rr = __half22float2(pr[i]);
            resv[2 * i] = rr.x; resv[2 * i + 1] = rr.y;
        }
        float r8[8];
#pragma unroll
        for (int half = 0; half < 2; half++) {
            int c = c0 + half * 4;
            float4 bb = *(const float4*)(cb + c);
            float4 gm = *(const float4*)(gamma + c);
            float4 bt = *(const float4*)(beta + c);
            float4 mn = *(const float4*)(mean + c);
            float4 vr = *(const float4*)(var + c);
            float* a = &acc[half * 4];
            float* rs = &resv[half * 4];
            r8[half * 4 + 0] = fmaxf((a[0] * iv + bb.x - mn.x) * rsqrtf(vr.x + BN_EPS) * gm.x + bt.x, 0.f) + rs[0];
            r8[half * 4 + 1] = fmaxf((a[1] * iv + bb.y - mn.y) * rsqrtf(vr.y + BN_EPS) * gm.y + bt.y, 0.f) + rs[1];
            r8[half * 4 + 2] = fmaxf((a[2] * iv + bb.z - mn.z) * rsqrtf(vr.z + BN_EPS) * gm.z + bt.z, 0.f) + rs[2];
            r8[half * 4 + 3] = fmaxf((a[3] * iv + bb.w - mn.w) * rsqrtf(vr.w + BN_EPS) * gm.w + bt.w, 0.f) + rs[3];
        }
        __half2 q0 = __floats2half2_rn(r8[0], r8[1]);
        __half2 q1 = __floats2half2_rn(r8[2], r8[3]);
        __half2 q2 = __floats2half2_rn(r8[4], r8[5]);
        __half2 q3 = __floats2half2_rn(r8[6], r8[7]);
        uint4 uo;
        uo.x = *(unsigned int*)&q0; uo.y = *(unsigned int*)&q1;
        uo.z = *(unsigned int*)&q2; uo.w = *(unsigned int*)&q3;
        *(uint4*)(h16 + (size_t)node * HDIM + c0) = uo;
    }
}

// ---- pooling: per-graph mean and max from fp16 h, writes fp16 gp -----------
__global__ void k_pool(const ushort* __restrict__ h16, const int* __restrict__ batch,
                       ushort* __restrict__ gp16) {
    int g = blockIdx.x;
    __shared__ int s_lo, s_hi;
    if (threadIdx.x == 0) {
        int lo = 0, hi = N_NODES;
        while (lo < hi) { int m = (lo + hi) >> 1; if (batch[m] < g) lo = m + 1; else hi = m; }
        s_lo = lo;
        hi = N_NODES;
        while (lo < hi) { int m = (lo + hi) >> 1; if (batch[m] < g + 1) lo = m + 1; else hi = m; }
        s_hi = lo;
    }
    __syncthreads();
    int lo = s_lo, hi = s_hi;
    int t = threadIdx.x;
    float sum = 0.0f, mx = -1e30f;
    for (int n = lo; n < hi; n++) {
        float v = __half2float(__ushort_as_half(h16[(size_t)n * HDIM + t]));
        sum += v;
        mx = fmaxf(mx, v);
    }
    float cntf = fmaxf((float)(hi - lo), 1.0f);
    float mean = sum / cntf;
    float mxo = (hi > lo) ? mx : 0.0f;
    gp16[(size_t)g * 2 * HDIM + t] = __half_as_ushort(__float2half(mean));
    gp16[(size_t)g * 2 * HDIM + HDIM + t] = __half_as_ushort(__float2half(mxo));
}

// ---- head GEMMs via MFMA ---------------------------------------------------
template <int K, bool OUT16>
__global__ void k_head_mfma(const ushort* __restrict__ A, const _Float16* __restrict__ Bt,
                            const float* __restrict__ bias, ushort* __restrict__ out16,
                            float* __restrict__ outf) {
    constexpr int LDKH = K + 8;
    __shared__ _Float16 hs[64 * LDKH];
    int block_r = blockIdx.x * 64;
    for (int i = threadIdx.x; i < 64 * (K / 8); i += blockDim.x) {
        int row = i / (K / 8);
        int c = (i % (K / 8)) * 8;
        *(uint4*)&hs[row * LDKH + c] = *(const uint4*)(A + (size_t)(block_r + row) * K + c);
    }
    __syncthreads();

    int wave = threadIdx.x >> 6;
    int lane = threadIdx.x & 63;
    int l16 = lane & 15;
    int quad = lane >> 4;
    int n0 = wave * 64;

    f32x4 acc[4][4] = {};
    for (int k0 = 0; k0 < K; k0 += 32) {
        half8 a[4], b[4];
#pragma unroll
        for (int ai = 0; ai < 4; ai++)
            a[ai] = *(const half8*)&hs[(ai * 16 + l16) * LDKH + k0 + quad * 8];
#pragma unroll
        for (int bj = 0; bj < 4; bj++)
            b[bj] = *(const half8*)&Bt[(size_t)(n0 + bj * 16 + l16) * K + k0 + quad * 8];
#pragma unroll
        for (int ai = 0; ai < 4; ai++)
#pragma unroll
            for (int bj = 0; bj < 4; bj++)
                acc[ai][bj] = __builtin_amdgcn_mfma_f32_16x16x32_f16(a[ai], b[bj], acc[ai][bj], 0, 0, 0);
    }

    int ncols = blockDim.x;   // waves*64
#pragma unroll
    for (int ai = 0; ai < 4; ai++) {
        int rowb = block_r + ai * 16 + quad * 4;
#pragma unroll
        for (int r = 0; r < 4; r++) {
            int row = rowb + r;
#pragma unroll
            for (int bj = 0; bj < 4; bj++) {
                int col = n0 + bj * 16 + l16;
                float v = fmaxf(acc[ai][bj][r] + bias[col], 0.f);
                if (OUT16)
                    out16[(size_t)row * ncols + col] = __half_as_ushort(__float2half(v));
                else
                    outf[(size_t)row * ncols + col] = v;
            }
        }
    }
}

__global__ void k_head3(const float* __restrict__ g2, const float* __restrict__ W3,
                        const float* __restrict__ b3, float* __restrict__ out) {
    int g = blockIdx.x;
    int t = threadIdx.x;  // 0..63
    __shared__ float gs[128];
    gs[t] = g2[(size_t)g * 128 + t];
    gs[64 + t] = g2[(size_t)g * 128 + 64 + t];
    __syncthreads();
    if (t < T_OUT) {
        float acc = b3[t];
#pragma unroll 8
        for (int k = 0; k < 128; k++) acc += gs[k] * W3[k * T_OUT + t];
        out[(size_t)g * T_OUT + t] = acc;
    }
}

extern "C" void kernel_launch(void* const* d_in, const int* in_sizes, int n_in,
                              void* d_out, int out_size, void* d_ws, size_t ws_size,
                              hipStream_t stream) {
    const float* x     = (const float*)d_in[0];
    const int*   ei    = (const int*)d_in[1];
    const int*   batch = (const int*)d_in[2];
    const float* projW = (const float*)d_in[3];
    const float* projb = (const float*)d_in[4];
    const float* convW = (const float*)d_in[5];
    const float* convb = (const float*)d_in[6];
    const float* gamma = (const float*)d_in[7];
    const float* beta  = (const float*)d_in[8];
    const float* mean  = (const float*)d_in[9];
    const float* var   = (const float*)d_in[10];
    const float* W1    = (const float*)d_in[11];
    const float* b1    = (const float*)d_in[12];
    const float* W2    = (const float*)d_in[13];
    const float* b2    = (const float*)d_in[14];
    const float* W3    = (const float*)d_in[15];
    const float* b3    = (const float*)d_in[16];
    float* out = (float*)d_out;

    // workspace layout (all segments 16B aligned)
    float*  wsf    = (float*)d_ws;
    float*  inv    = wsf;                        // NPAD f
    int*    cnt    = (int*)(wsf + NPAD);         // NPAD i
    int*    rowptr = cnt + NPAD;                 // NPAD i
    int*    wpos   = rowptr + NPAD;              // NPAD i
    int*    iscan  = wpos + NPAD;                // NPAD i
    int*    bsum   = iscan + NPAD;               // 256 i
    int*    boff   = bsum + 256;                 // 256 i
    ushort* csr    = (ushort*)(boff + 256);      // 800256 u16
    ushort* hWh    = csr + 800256;               // N*H fp16 (messages)
    ushort* h16    = hWh + (size_t)N_NODES * HDIM;            // N*H fp16 residual stream
    ushort* gp16   = h16 + (size_t)N_NODES * HDIM;            // G*512 fp16
    ushort* g1h    = gp16 + (size_t)G_GRAPHS * 512;           // G*256 fp16
    float*  g2     = (float*)(g1h + (size_t)G_GRAPHS * 256);  // G*128 f32
    _Float16* Wt   = (_Float16*)(g2 + (size_t)G_GRAPHS * 128); // WT_TOT fp16

    // ---- CSR build + weight transposes ----
    hipMemsetAsync(cnt, 0, NPAD * sizeof(int), stream);
    k_deg_count<<<(E_EDGES + 255) / 256, 256, 0, stream>>>(ei + E_EDGES, cnt);
    k_scan1<<<NBLK, 256, 0, stream>>>(cnt, iscan, bsum);
    k_scan2<<<1, 256, 0, stream>>>(bsum, boff);
    k_scan3<<<NBLK, 256, 0, stream>>>(cnt, iscan, boff, rowptr, wpos, inv);
    k_scatter<<<(E_EDGES + 255) / 256, 256, 0, stream>>>(ei, wpos, csr);
    k_wcvt_all<<<(WT_TOT + 255) / 256, 256, 0, stream>>>(convW, projW, W1, W2, Wt);

    // ---- proj (MFMA) ----
    int gemm_blocks = (N_NODES + 63) / 64;
    k_proj_mfma<<<gemm_blocks, 256, 0, stream>>>(x, Wt + WT_PROJ, projb, h16, N_NODES);

    // ---- GCN layers ----
    for (int l = 0; l < L_LAYERS; l++) {
        k_gemm_mfma<<<gemm_blocks, 256, 0, stream>>>(h16, Wt + WT_CONV + (size_t)l * HDIM * HDIM,
                                                     inv, (_Float16*)hWh, N_NODES);
        k_aggr<<<(N_NODES + 3) / 4, 256, 0, stream>>>(rowptr, csr, hWh, inv,
                                                      convb + l * HDIM, gamma + l * HDIM,
                                                      beta + l * HDIM, mean + l * HDIM,
                                                      var + l * HDIM, h16);
    }

    // ---- pool + head ----
    k_pool<<<G_GRAPHS, HDIM, 0, stream>>>(h16, batch, gp16);
    k_head_mfma<512, true><<<G_GRAPHS / 64, 256, 0, stream>>>(gp16, Wt + WT_H1, b1, g1h, nullptr);
    k_head_mfma<256, false><<<G_GRAPHS / 64, 128, 0, stream>>>(g1h, Wt + WT_H2, b2, nullptr, g2);
    k_head3<<<G_GRAPHS, 64, 0, stream>>>(g2, W3, b3, out);
}